// Round 5
// baseline (167.953 us; speedup 1.0000x reference)
//
#include <hip/hip_runtime.h>

// PrimalDualNetwork: 10-iter Chambolle-Pock ROF on 2048x2048 fp32.
// R5: fully-fused single kernel + (a) shrinking active region (cone
// contracts 1px/iter; per-unit precomputed deactivation threshold d,
// active iff rem >= d; monotone freeze => stale state never read by
// needed region), (b) 512-thread blocks (64x32 tile, plane 52x88,
// NPASS=3) => 3-4 resident blocks/CU so barrier stalls overlap across
// blocks (R4: 2 blocks, VALUBusy 57%).
// VGPR diet for occupancy: own xt/p re-read from LDS (conflict-free
// contiguous b128/b64); only scalars xt0/pH3 kept for cross-lane shuffles
// (shuffles hoisted out of the act-branch); img copy in fp16.

namespace {
constexpr int M = 2048, N = 2048;
constexpr float SIGMA     = 1.0f / (7.0f * 0.01f);
constexpr float INV_SIGMA = 7.0f * 0.01f;
constexpr float TAU       = 0.01f;
constexpr float LT        = 4.0f * 0.01f;
constexpr float INV_DEN   = 1.0f / (1.0f + 4.0f * 0.01f);
constexpr int TW = 64, TH = 32;     // output tile
constexpr int PC = 88;              // plane cols (12 + 64 + 12)
constexpr int PR = 52;              // plane rows (10 + 32 + 10)
constexpr int UPR = 22;             // float4 units per row == PC/4
constexpr int PROC = 51;            // rows 0..50 processed (51 read-only)
constexpr int NU = PROC * UPR;      // 1122
constexpr int NT = 512;             // 8 waves
constexpr int NPASS = 3;
} // namespace

typedef _Float16 h4 __attribute__((ext_vector_type(4)));

__device__ inline h4 h4splat(float v) {
    _Float16 s = (_Float16)v;
    return (h4){s, s, s, s};
}
__device__ inline int imax(int a, int b) { return a > b ? a : b; }

__global__ __launch_bounds__(NT, 6) void pd_fused(
    const float* __restrict__ img, float* __restrict__ out,
    const float* __restrict__ w1p, const float* __restrict__ w2p)
{
    __shared__ __align__(16) float    sXT[PR * PC];   // 18304 B
    __shared__ __align__(16) _Float16 sPH[PR * PC];   //  9152 B
    __shared__ __align__(16) _Float16 sPV[PR * PC];   //  9152 B

    const int tid  = threadIdx.x;
    const int lane = tid & 63;
    const int c0 = blockIdx.x * TW, r0 = blockIdx.y * TH;
    const int gr0 = r0 - 10, gc0 = c0 - 12;
    const float w1 = w1p[0], w2 = w2p[0];

    // per-pass invariants + deactivation threshold d (active iff rem >= d)
    int u_[NPASS], bF_[NPASS], gi_[NPASS], gjb_[NPASS], dth_[NPASS];
    #pragma unroll
    for (int p = 0; p < NPASS; ++p) {
        int u = tid + p * NT;
        int li = u / UPR, uj = u - li * UPR;
        int lc = uj * 4;
        u_[p] = u; bF_[p] = u * 4;
        gi_[p] = gr0 + li; gjb_[p] = gc0 + lc;
        int d = imax(imax(9 - li, li - 41), imax(8 - lc, lc - 75));
        d = imax(d, 0);
        if (u >= NU) d = 100;                  // never active
        dth_[p] = d;
    }

    // ---- stage img -> sXT (full plane incl row 51; 0 outside image) ----
    #pragma unroll
    for (int p = 0; p < NPASS; ++p) {
        int su = tid + p * NT;
        if (su < PR * UPR) {
            int li = su / UPR, uj = su - li * UPR;
            int gi = gr0 + li, gj = gc0 + uj * 4;
            float4 v = make_float4(0.f, 0.f, 0.f, 0.f);
            if ((unsigned)gi < (unsigned)M && (unsigned)gj <= (unsigned)(N - 4))
                v = *(const float4*)&img[(size_t)gi * N + gj];
            *(float4*)&sXT[su * 4] = v;
        }
    }
    __syncthreads();

    // register state (lean): x fp32, img fp16, y/sw fp16 packed,
    // xt0/pH3 scalars for cross-lane shuffles.
    float xr[NPASS][4], xt0_[NPASS], pH3_[NPASS];
    h4 xi_[NPASS], yh[NPASS], yv[NPASS], swh[NPASS], swv[NPASS];

    // ---- init (== dual(0), rem=9: all u<NU active): w, y0, p0 ----
    #pragma unroll
    for (int p = 0; p < NPASS; ++p) {
        int u = u_[p], bF = bF_[p];
        float4 c = make_float4(0.f, 0.f, 0.f, 0.f);
        if (u < NU) c = *(const float4*)&sXT[bF];
        float rr = __shfl_down(c.x, 1, 64);
        if (u < NU) {
            if (lane == 63) rr = sXT[bF + 4];
            float4 dn = *(const float4*)&sXT[bF + PC];
            float ca[4] = {c.x, c.y, c.z, c.w};
            float da[4] = {dn.x, dn.y, dn.z, dn.w};
            bool vok = gi_[p] < M - 1;
            h4 ph, pv;
            #pragma unroll
            for (int l = 0; l < 4; ++l) {
                float nxt = (l < 3) ? ca[l + 1] : rr;
                bool hok = (gjb_[p] + l) < N - 1;
                float gh = hok ? nxt - ca[l] : 0.f;
                float gv = vok ? da[l] - ca[l] : 0.f;
                float wh = fmaf(w2, __expf(-fabsf(gh)), w1);
                float wv = fmaf(w2, __expf(-fabsf(gv)), w1);
                float y0h = fminf(fmaxf(gh * fmaf(SIGMA, wh, 1.f), -1.f), 1.f);
                float y0v = fminf(fmaxf(gv * fmaf(SIGMA, wv, 1.f), -1.f), 1.f);
                yh[p][l]  = (_Float16)y0h;  yv[p][l]  = (_Float16)y0v;
                swh[p][l] = (_Float16)(hok ? SIGMA * wh : 0.f);
                swv[p][l] = (_Float16)(vok ? SIGMA * wv : 0.f);
                ph[l] = (_Float16)(wh * y0h);
                pv[l] = (_Float16)(wv * y0v);
                xr[p][l] = ca[l];
                xi_[p][l] = (_Float16)ca[l];
            }
            *(h4*)&sPH[bF] = ph; *(h4*)&sPV[bF] = pv;
            pH3_[p] = (float)ph[3];
            xt0_[p] = c.x;
        }
    }
    __syncthreads();

    // ---- dual(t>=1): y += sw*grad(xt) clamp; p = (sw*y)/sigma -> LDS ----
    auto dual = [&](int rem) {
        #pragma unroll
        for (int p = 0; p < NPASS; ++p) {
            float rr = __shfl_down(xt0_[p], 1, 64);   // unconditional (exec-safe)
            if (rem >= dth_[p]) {
                int bF = bF_[p];
                float4 c  = *(const float4*)&sXT[bF];
                if (lane == 63) rr = sXT[bF + 4];
                float4 dn = *(const float4*)&sXT[bF + PC];
                h4 ghh, gvh;
                ghh[0] = (_Float16)(c.y - c.x); ghh[1] = (_Float16)(c.z - c.y);
                ghh[2] = (_Float16)(c.w - c.z); ghh[3] = (_Float16)(rr  - c.w);
                gvh[0] = (_Float16)(dn.x - c.x); gvh[1] = (_Float16)(dn.y - c.y);
                gvh[2] = (_Float16)(dn.z - c.z); gvh[3] = (_Float16)(dn.w - c.w);
                h4 nh = yh[p] + swh[p] * ghh;   // masked sw => border y stays 0
                h4 nv = yv[p] + swv[p] * gvh;
                nh = __builtin_elementwise_min(__builtin_elementwise_max(nh, h4splat(-1.f)), h4splat(1.f));
                nv = __builtin_elementwise_min(__builtin_elementwise_max(nv, h4splat(-1.f)), h4splat(1.f));
                yh[p] = nh; yv[p] = nv;
                h4 is = h4splat(INV_SIGMA);
                h4 ph = (swh[p] * nh) * is;     // == w*y
                h4 pv = (swv[p] * nv) * is;
                *(h4*)&sPH[bF] = ph; *(h4*)&sPV[bF] = pv;
                pH3_[p] = (float)ph[3];
            }
        }
    };

    // ---- primal: x = (x + tau*div(p) + lt*img)/(1+lt); xt = 1.5x-0.5xo ----
    auto primal = [&](int rem) {
        #pragma unroll
        for (int p = 0; p < NPASS; ++p) {
            float phl = __shfl_up(pH3_[p], 1, 64);    // unconditional (exec-safe)
            if (rem >= dth_[p]) {
                int u = u_[p], bF = bF_[p];
                int bu = (u >= UPR) ? bF - PC : bF;   // up unit (row0 never needed)
                h4 pvu = *(const h4*)&sPV[bu];
                h4 ph  = *(const h4*)&sPH[bF];
                h4 pv  = *(const h4*)&sPV[bF];
                if (lane == 0 && u > 0) phl = (float)sPH[bF - 1];
                bool iok = gi_[p] >= 1;
                float xtv[4];
                #pragma unroll
                for (int l = 0; l < 4; ++l) {
                    float p_h  = (float)ph[l];
                    float p_hm = (l == 0) ? phl : (float)ph[l - 1];
                    if (gjb_[p] + l < 1) p_hm = 0.f;         // image left edge
                    float p_v  = (float)pv[l];
                    float p_vm = iok ? (float)pvu[l] : 0.f;  // image top edge
                    float dvg  = (p_h - p_hm) + (p_v - p_vm);
                    float xo = xr[p][l];
                    float xn = (fmaf(TAU, dvg, xo) + LT * (float)xi_[p][l]) * INV_DEN;
                    xr[p][l] = xn;
                    xtv[l] = fmaf(1.5f, xn, -0.5f * xo);     // THETA = 0.5
                }
                *(float4*)&sXT[bF] = make_float4(xtv[0], xtv[1], xtv[2], xtv[3]);
                xt0_[p] = xtv[0];
            }
        }
    };

    primal(9);                 // t=0 (dual(0) fused into init)
    __syncthreads();
    #pragma unroll 1
    for (int t = 1; t < 10; ++t) {
        int rem = 9 - t;
        dual(rem);
        __syncthreads();
        primal(rem);
        __syncthreads();
    }

    // ---- output xt(9): plane rows 10..41, cols 12..75 ----
    {
        int row = tid >> 4;          // 0..31
        int cu  = tid & 15;          // 0..15
        float4 v = *(const float4*)&sXT[(10 + row) * PC + 12 + 4 * cu];
        *(float4*)&out[(size_t)(r0 + row) * N + (c0 + 4 * cu)] = v;
    }
}

extern "C" void kernel_launch(void* const* d_in, const int* in_sizes, int n_in,
                              void* d_out, int out_size, void* d_ws, size_t ws_size,
                              hipStream_t stream)
{
    const float* img = (const float*)d_in[0];
    const float* w1  = (const float*)d_in[1];
    const float* w2  = (const float*)d_in[2];
    float* out = (float*)d_out;

    dim3 grid(N / TW, M / TH);   // 32 x 64 = 2048 blocks
    pd_fused<<<grid, NT, 0, stream>>>(img, out, w1, w2);
}

// Round 6
// 128.170 us; speedup vs baseline: 1.3104x; 1.3104x over previous
//
#include <hip/hip_runtime.h>

// PrimalDualNetwork: 10-iter Chambolle-Pock ROF on 2048x2048 fp32.
// R6 = R4 (proven: 78.5us kernel, no spills) + shrinking-cone pass guard
// + q=sigma*w*y folding (saves 2 pk_muls/unit-iter in dual).
//  - 64x64 tile + 10px halo, plane 84x88, origin (r0-10, c0-12).
//  - NT=1024, NPASS=2, __launch_bounds__(1024,4): R5 post-mortem showed the
//    2nd launch_bounds arg behaves as min BLOCKS/CU (VGPR cap 512/(blk*waves/4));
//    (1024,4) -> 64-VGPR cap, demand ~44, no scratch spills (R5's (512,6)
//    capped at 42 -> 138MB spill traffic -> regression).
//  - Cone guard: unit active iff rem >= d, d = max(9-li, li-73, 8-lc, lc-75, 0)
//    (tail units d=100). Skipped units are outside the backward-induction
//    need-set => frozen state never read by needed computations. Savings are
//    wave-granular: whole-row deactivation + pass-2 dead tail.
//  - LDS: sXT fp32 (down-neighbor xt), sQH/sQV fp16 (q = sigma*w*y; up/left
//    neighbor reads). Own xt/q stay in registers; left/right via shuffles
//    (hoisted outside guards for exec-safety).

namespace {
constexpr int M = 2048, N = 2048;
constexpr float SIGMA     = 1.0f / (7.0f * 0.01f);
constexpr float TAU       = 0.01f;
constexpr float TAUIS     = TAU * (7.0f * 0.01f);    // tau/sigma (q-scaled div)
constexpr float LT        = 4.0f * 0.01f;
constexpr float INV_DEN   = 1.0f / (1.0f + 4.0f * 0.01f);
constexpr int TW = 64, TH = 64;     // output tile
constexpr int PC = 88;              // plane cols (12 + 64 + 12)
constexpr int PR = 84;              // plane rows (10 + 64 + 10)
constexpr int UPR = 22;             // float4 units per row == PC/4 (full cover)
constexpr int PROC = 83;            // rows 0..82 processed (83 read-only)
constexpr int NU = PROC * UPR;      // 1826
constexpr int NT = 1024;            // 16 waves
constexpr int NPASS = 2;
} // namespace

typedef _Float16 h4 __attribute__((ext_vector_type(4)));

__device__ inline h4 h4splat(float v) {
    _Float16 s = (_Float16)v;
    return (h4){s, s, s, s};
}
__device__ inline int imax(int a, int b) { return a > b ? a : b; }

__global__ __launch_bounds__(NT, 4) void pd_fused(
    const float* __restrict__ img, float* __restrict__ out,
    const float* __restrict__ w1p, const float* __restrict__ w2p)
{
    __shared__ __align__(16) float    sXT[PR * PC];   // 29568 B
    __shared__ __align__(16) _Float16 sQH[PR * PC];   // 14784 B
    __shared__ __align__(16) _Float16 sQV[PR * PC];   // 14784 B

    const int tid  = threadIdx.x;
    const int lane = tid & 63;
    const int c0 = blockIdx.x * TW, r0 = blockIdx.y * TH;
    const int gr0 = r0 - 10, gc0 = c0 - 12;
    const float w1 = w1p[0], w2 = w2p[0];

    // per-pass invariants + cone deactivation threshold
    int u_[NPASS], bF_[NPASS], gi_[NPASS], gjb_[NPASS], dth_[NPASS];
    #pragma unroll
    for (int p = 0; p < NPASS; ++p) {
        int u = tid + p * NT;
        int li = u / UPR, uj = u - li * UPR;
        int lc = uj * 4;
        u_[p] = u; bF_[p] = u * 4;
        gi_[p] = gr0 + li; gjb_[p] = gc0 + lc;
        int d = imax(imax(9 - li, li - 73), imax(8 - lc, lc - 75));
        d = imax(d, 0);
        if (u >= NU) d = 100;
        dth_[p] = d;
    }

    // ---- stage img -> sXT (full plane incl row 83; 0 outside image) ----
    #pragma unroll
    for (int p = 0; p < NPASS; ++p) {
        int su = tid + p * NT;
        if (su < PR * UPR) {
            int li = su / UPR, uj = su - li * UPR;
            int gi = gr0 + li, gj = gc0 + uj * 4;
            float4 v = make_float4(0.f, 0.f, 0.f, 0.f);
            if ((unsigned)gi < (unsigned)M && (unsigned)gj <= (unsigned)(N - 4))
                v = *(const float4*)&img[(size_t)gi * N + gj];
            *(float4*)&sXT[su * 4] = v;
        }
    }
    __syncthreads();

    // register state
    float xr[NPASS][4], xi[NPASS][4], xt[NPASS][4], q3_[NPASS];
    h4 yh[NPASS], yv[NPASS], swh[NPASS], swv[NPASS], qH[NPASS], qV[NPASS];

    // ---- init (== dual(0)): w (masked sigma*w), y0, q0 = sw*y0 ----
    #pragma unroll
    for (int p = 0; p < NPASS; ++p) {
        int u = u_[p], bF = bF_[p];
        float4 c = make_float4(0.f, 0.f, 0.f, 0.f);
        if (u < NU) c = *(const float4*)&sXT[bF];
        float rr = __shfl_down(c.x, 1, 64);
        if (u < NU) {
            if (lane == 63) rr = sXT[bF + 4];
            float4 dn = *(const float4*)&sXT[bF + PC];
            float ca[4] = {c.x, c.y, c.z, c.w};
            float da[4] = {dn.x, dn.y, dn.z, dn.w};
            bool vok = gi_[p] < M - 1;
            #pragma unroll
            for (int l = 0; l < 4; ++l) {
                float nxt = (l < 3) ? ca[l + 1] : rr;
                bool hok = (gjb_[p] + l) < N - 1;
                float gh = hok ? nxt - ca[l] : 0.f;
                float gv = vok ? da[l] - ca[l] : 0.f;
                float wh = fmaf(w2, __expf(-fabsf(gh)), w1);
                float wv = fmaf(w2, __expf(-fabsf(gv)), w1);
                float y0h = fminf(fmaxf(gh * fmaf(SIGMA, wh, 1.f), -1.f), 1.f);
                float y0v = fminf(fmaxf(gv * fmaf(SIGMA, wv, 1.f), -1.f), 1.f);
                float sh = hok ? SIGMA * wh : 0.f;
                float sv = vok ? SIGMA * wv : 0.f;
                yh[p][l]  = (_Float16)y0h;  yv[p][l]  = (_Float16)y0v;
                swh[p][l] = (_Float16)sh;   swv[p][l] = (_Float16)sv;
                qH[p][l]  = (_Float16)(sh * y0h);
                qV[p][l]  = (_Float16)(sv * y0v);
                xr[p][l] = ca[l]; xi[p][l] = ca[l]; xt[p][l] = ca[l];
            }
            *(h4*)&sQH[bF] = qH[p]; *(h4*)&sQV[bF] = qV[p];
            q3_[p] = (float)qH[p][3];
        }
    }
    __syncthreads();

    // ---- dual(t>=1): y = clamp(y + sw*grad(xt)); q = sw*y ----
    auto dual = [&](int rem) {
        #pragma unroll
        for (int p = 0; p < NPASS; ++p) {
            float rr = __shfl_down(xt[p][0], 1, 64);   // unconditional (exec-safe)
            if (rem >= dth_[p]) {
                int bF = bF_[p];
                if (lane == 63) rr = sXT[bF + 4];
                float4 dn = *(const float4*)&sXT[bF + PC];
                float da[4] = {dn.x, dn.y, dn.z, dn.w};
                h4 ghh, gvh;
                #pragma unroll
                for (int l = 0; l < 4; ++l) {
                    float nxt = (l < 3) ? xt[p][l + 1] : rr;
                    ghh[l] = (_Float16)(nxt - xt[p][l]);
                    gvh[l] = (_Float16)(da[l] - xt[p][l]);
                }
                h4 nh = yh[p] + swh[p] * ghh;   // masked sw => border y stays 0
                h4 nv = yv[p] + swv[p] * gvh;
                nh = __builtin_elementwise_min(__builtin_elementwise_max(nh, h4splat(-1.f)), h4splat(1.f));
                nv = __builtin_elementwise_min(__builtin_elementwise_max(nv, h4splat(-1.f)), h4splat(1.f));
                yh[p] = nh; yv[p] = nv;
                h4 qh = swh[p] * nh;            // q = sigma*w*y
                h4 qv = swv[p] * nv;
                qH[p] = qh; qV[p] = qv;
                *(h4*)&sQH[bF] = qh; *(h4*)&sQV[bF] = qv;
                q3_[p] = (float)qh[3];
            }
        }
    };

    // ---- primal: x = (x + (tau/sigma)*div(q) + lt*img)/(1+lt); xt = 1.5x-0.5xo
    auto primal = [&](int rem) {
        #pragma unroll
        for (int p = 0; p < NPASS; ++p) {
            float qhl = __shfl_up(q3_[p], 1, 64);     // unconditional (exec-safe)
            if (rem >= dth_[p]) {
                int u = u_[p], bF = bF_[p];
                int bu = (u >= UPR) ? bF - PC : bF;   // up unit (row0 never needed)
                h4 qvu = *(const h4*)&sQV[bu];
                if (lane == 0 && u > 0) qhl = (float)sQH[bF - 1];
                bool iok = gi_[p] >= 1;
                float xtv[4];
                #pragma unroll
                for (int l = 0; l < 4; ++l) {
                    float p_h  = (float)qH[p][l];
                    float p_hm = (l == 0) ? qhl : (float)qH[p][l - 1];
                    if (gjb_[p] + l < 1) p_hm = 0.f;         // image left edge
                    float p_v  = (float)qV[p][l];
                    float p_vm = iok ? (float)qvu[l] : 0.f;  // image top edge
                    float dvg  = (p_h - p_hm) + (p_v - p_vm);
                    float xo = xr[p][l];
                    float xn = (fmaf(TAUIS, dvg, xo) + LT * xi[p][l]) * INV_DEN;
                    xr[p][l] = xn;
                    float v = fmaf(1.5f, xn, -0.5f * xo);    // THETA = 0.5
                    xt[p][l] = v; xtv[l] = v;
                }
                *(float4*)&sXT[bF] = make_float4(xtv[0], xtv[1], xtv[2], xtv[3]);
            }
        }
    };

    primal(9);                 // t=0 (dual(0) fused into init)
    __syncthreads();
    #pragma unroll 1
    for (int t = 1; t < 10; ++t) {
        int rem = 9 - t;
        dual(rem);
        __syncthreads();
        primal(rem);
        __syncthreads();
    }

    // ---- output xt(9): plane rows 10..73, cols 12..75 ----
    {
        int row = tid >> 4;          // 0..63
        int cu  = tid & 15;          // 0..15
        float4 v = *(const float4*)&sXT[(10 + row) * PC + 12 + 4 * cu];
        *(float4*)&out[(size_t)(r0 + row) * N + (c0 + 4 * cu)] = v;
    }
}

extern "C" void kernel_launch(void* const* d_in, const int* in_sizes, int n_in,
                              void* d_out, int out_size, void* d_ws, size_t ws_size,
                              hipStream_t stream)
{
    const float* img = (const float*)d_in[0];
    const float* w1  = (const float*)d_in[1];
    const float* w2  = (const float*)d_in[2];
    float* out = (float*)d_out;

    dim3 grid(N / TW, M / TH);   // 32 x 32 = 1024 blocks
    pd_fused<<<grid, NT, 0, stream>>>(img, out, w1, w2);
}

// Round 7
// 120.164 us; speedup vs baseline: 1.3977x; 1.0666x over previous
//
#include <hip/hip_runtime.h>

// PrimalDualNetwork: 10-iter Chambolle-Pock ROF on 2048x2048 fp32.
// R7 = R6 skeleton (proven 68.7us kernel) + primal op-diet:
//  (a) FULL DEMASKING: sigma*w := 0 for any unit whose SOURCE pixel is
//      off-image => q == 0 there forever => primal's image-edge cndmasks
//      (iok / left-edge) deleted; boundaries are data, not control.
//  (b) packed-fp16 divergence: q already fp16-quantized (error-neutral
//      since R3) => div(q) in v_pk_sub/add_f16; only 4 cvts to fp32 for
//      the x-update (xt/x stay fp32 — the precision-critical path).
//  (c) left q scalar via ds_read_u16 (2-way conflict = free) instead of
//      shuffle + lane-0 fixup.
// Structure: 64x64 tile + 10px halo, plane 84x88, origin (r0-10,c0-12),
// NT=1024, NPASS=2, launch_bounds(1024,4) (R5 lesson: tighter bounds
// caused a 42-VGPR cap -> 120MB scratch spills -> regression).
// Cone guard: active iff rem >= d (monotone freeze; junk provably outside
// the backward-induction need-set; all values finite => no NaN escape).

namespace {
constexpr int M = 2048, N = 2048;
constexpr float SIGMA     = 1.0f / (7.0f * 0.01f);
constexpr float TAU       = 0.01f;
constexpr float TAUIS     = TAU * (7.0f * 0.01f);    // tau/sigma (q-scaled div)
constexpr float LT        = 4.0f * 0.01f;
constexpr float INV_DEN   = 1.0f / (1.0f + 4.0f * 0.01f);
constexpr int TW = 64, TH = 64;     // output tile
constexpr int PC = 88;              // plane cols (12 + 64 + 12)
constexpr int PR = 84;              // plane rows (10 + 64 + 10)
constexpr int UPR = 22;             // float4 units per row == PC/4 (full cover)
constexpr int PROC = 83;            // rows 0..82 processed (83 read-only)
constexpr int NU = PROC * UPR;      // 1826
constexpr int NT = 1024;            // 16 waves
constexpr int NPASS = 2;
} // namespace

typedef _Float16 h4 __attribute__((ext_vector_type(4)));

__device__ inline h4 h4splat(float v) {
    _Float16 s = (_Float16)v;
    return (h4){s, s, s, s};
}
__device__ inline int imax(int a, int b) { return a > b ? a : b; }

__global__ __launch_bounds__(NT, 4) void pd_fused(
    const float* __restrict__ img, float* __restrict__ out,
    const float* __restrict__ w1p, const float* __restrict__ w2p)
{
    __shared__ __align__(16) float    sXT[PR * PC];   // 29568 B
    __shared__ __align__(16) _Float16 sQH[PR * PC];   // 14784 B
    __shared__ __align__(16) _Float16 sQV[PR * PC];   // 14784 B

    const int tid  = threadIdx.x;
    const int lane = tid & 63;
    const int c0 = blockIdx.x * TW, r0 = blockIdx.y * TH;
    const int gr0 = r0 - 10, gc0 = c0 - 12;
    const float w1 = w1p[0], w2 = w2p[0];

    // per-pass invariants + cone deactivation threshold
    int u_[NPASS], bF_[NPASS], gi_[NPASS], gjb_[NPASS], dth_[NPASS];
    #pragma unroll
    for (int p = 0; p < NPASS; ++p) {
        int u = tid + p * NT;
        int li = u / UPR, uj = u - li * UPR;
        int lc = uj * 4;
        u_[p] = u; bF_[p] = u * 4;
        gi_[p] = gr0 + li; gjb_[p] = gc0 + lc;
        int d = imax(imax(9 - li, li - 73), imax(8 - lc, lc - 75));
        d = imax(d, 0);
        if (u >= NU) d = 100;
        dth_[p] = d;
    }

    // ---- stage img -> sXT (full plane incl row 83; 0 outside image) ----
    #pragma unroll
    for (int p = 0; p < NPASS; ++p) {
        int su = tid + p * NT;
        if (su < PR * UPR) {
            int li = su / UPR, uj = su - li * UPR;
            int gi = gr0 + li, gj = gc0 + uj * 4;
            float4 v = make_float4(0.f, 0.f, 0.f, 0.f);
            if ((unsigned)gi < (unsigned)M && (unsigned)gj <= (unsigned)(N - 4))
                v = *(const float4*)&img[(size_t)gi * N + gj];
            *(float4*)&sXT[su * 4] = v;
        }
    }
    __syncthreads();

    // register state
    float xr[NPASS][4], xi[NPASS][4], xt[NPASS][4];
    h4 yh[NPASS], yv[NPASS], swh[NPASS], swv[NPASS], qH[NPASS], qV[NPASS];

    // ---- init (== dual(0)): masked sigma*w (0 for off-image SOURCE pixel
    //      or forward-diff at last col/row), y0, q0 = sw*y0 ----
    #pragma unroll
    for (int p = 0; p < NPASS; ++p) {
        int u = u_[p], bF = bF_[p];
        float4 c = make_float4(0.f, 0.f, 0.f, 0.f);
        if (u < NU) c = *(const float4*)&sXT[bF];
        float rr = __shfl_down(c.x, 1, 64);
        if (u < NU) {
            if (lane == 63) rr = sXT[bF + 4];
            float4 dn = *(const float4*)&sXT[bF + PC];
            float ca[4] = {c.x, c.y, c.z, c.w};
            float da[4] = {dn.x, dn.y, dn.z, dn.w};
            int gi = gi_[p];
            bool rok = (unsigned)gi < (unsigned)M;          // row in image
            bool vok = rok && (gi < M - 1);
            #pragma unroll
            for (int l = 0; l < 4; ++l) {
                int gj = gjb_[p] + l;
                bool cok = (unsigned)gj < (unsigned)N;      // col in image
                bool hok = rok && cok && (gj < N - 1);
                bool vk  = vok && cok;
                float nxt = (l < 3) ? ca[l + 1] : rr;
                float gh = hok ? nxt - ca[l] : 0.f;
                float gv = vk  ? da[l] - ca[l] : 0.f;
                float wh = fmaf(w2, __expf(-fabsf(gh)), w1);
                float wv = fmaf(w2, __expf(-fabsf(gv)), w1);
                float y0h = fminf(fmaxf(gh * fmaf(SIGMA, wh, 1.f), -1.f), 1.f);
                float y0v = fminf(fmaxf(gv * fmaf(SIGMA, wv, 1.f), -1.f), 1.f);
                float sh = hok ? SIGMA * wh : 0.f;
                float sv = vk  ? SIGMA * wv : 0.f;
                yh[p][l]  = (_Float16)y0h;  yv[p][l]  = (_Float16)y0v;
                swh[p][l] = (_Float16)sh;   swv[p][l] = (_Float16)sv;
                qH[p][l]  = (_Float16)(sh * y0h);
                qV[p][l]  = (_Float16)(sv * y0v);
                xr[p][l] = ca[l]; xi[p][l] = ca[l]; xt[p][l] = ca[l];
            }
            *(h4*)&sQH[bF] = qH[p]; *(h4*)&sQV[bF] = qV[p];
        }
    }
    __syncthreads();

    // ---- dual(t>=1): y = clamp(y + sw*grad(xt)); q = sw*y ----
    auto dual = [&](int rem) {
        #pragma unroll
        for (int p = 0; p < NPASS; ++p) {
            float rr = __shfl_down(xt[p][0], 1, 64);   // unconditional (exec-safe)
            if (rem >= dth_[p]) {
                int bF = bF_[p];
                if (lane == 63) rr = sXT[bF + 4];
                float4 dn = *(const float4*)&sXT[bF + PC];
                float da[4] = {dn.x, dn.y, dn.z, dn.w};
                h4 ghh, gvh;
                #pragma unroll
                for (int l = 0; l < 4; ++l) {
                    float nxt = (l < 3) ? xt[p][l + 1] : rr;
                    ghh[l] = (_Float16)(nxt - xt[p][l]);   // fp32 sub, pk-cvt
                    gvh[l] = (_Float16)(da[l] - xt[p][l]);
                }
                h4 nh = yh[p] + swh[p] * ghh;   // sw=0 masks borders/off-image
                h4 nv = yv[p] + swv[p] * gvh;
                nh = __builtin_elementwise_min(__builtin_elementwise_max(nh, h4splat(-1.f)), h4splat(1.f));
                nv = __builtin_elementwise_min(__builtin_elementwise_max(nv, h4splat(-1.f)), h4splat(1.f));
                yh[p] = nh; yv[p] = nv;
                h4 qh = swh[p] * nh;            // q = sigma*w*y
                h4 qv = swv[p] * nv;
                qH[p] = qh; qV[p] = qv;
                *(h4*)&sQH[bF] = qh; *(h4*)&sQV[bF] = qv;
            }
        }
    };

    // ---- primal: x = (x + (tau/sigma)*div(q) + lt*img)/(1+lt); xt=1.5x-0.5xo
    //      div fully packed fp16 (q is fp16-quantized anyway); NO edge masks
    //      (demasked via sw=0 => q=0 at off-image sources). ----
    auto primal = [&](int rem) {
        #pragma unroll
        for (int p = 0; p < NPASS; ++p) {
            if (rem >= dth_[p]) {
                int u = u_[p], bF = bF_[p];
                int bu = (u >= UPR) ? bF - PC : bF;     // row-0 junk tolerated
                h4 qvu = *(const h4*)&sQV[bu];
                _Float16 qhl = sQH[imax(bF - 1, 0)];    // left scalar (2-way ok)
                h4 qsh;                                  // qH shifted right by 1
                qsh[0] = qhl; qsh[1] = qH[p][0]; qsh[2] = qH[p][1]; qsh[3] = qH[p][2];
                h4 dvg = (qH[p] - qsh) + (qV[p] - qvu);  // v_pk_sub/add_f16
                float xtv[4];
                #pragma unroll
                for (int l = 0; l < 4; ++l) {
                    float dv = (float)dvg[l];
                    float xo = xr[p][l];
                    float xn = (fmaf(TAUIS, dv, xo) + LT * xi[p][l]) * INV_DEN;
                    xr[p][l] = xn;
                    float v = fmaf(0.5f, xn - xo, xn);   // 1.5x - 0.5xo
                    xt[p][l] = v; xtv[l] = v;
                }
                *(float4*)&sXT[bF] = make_float4(xtv[0], xtv[1], xtv[2], xtv[3]);
            }
        }
    };

    primal(9);                 // t=0 (dual(0) fused into init)
    __syncthreads();
    #pragma unroll 1
    for (int t = 1; t < 10; ++t) {
        int rem = 9 - t;
        dual(rem);
        __syncthreads();
        primal(rem);
        __syncthreads();
    }

    // ---- output xt(9): plane rows 10..73, cols 12..75 ----
    {
        int row = tid >> 4;          // 0..63
        int cu  = tid & 15;          // 0..15
        float4 v = *(const float4*)&sXT[(10 + row) * PC + 12 + 4 * cu];
        *(float4*)&out[(size_t)(r0 + row) * N + (c0 + 4 * cu)] = v;
    }
}

extern "C" void kernel_launch(void* const* d_in, const int* in_sizes, int n_in,
                              void* d_out, int out_size, void* d_ws, size_t ws_size,
                              hipStream_t stream)
{
    const float* img = (const float*)d_in[0];
    const float* w1  = (const float*)d_in[1];
    const float* w2  = (const float*)d_in[2];
    float* out = (float*)d_out;

    dim3 grid(N / TW, M / TH);   // 32 x 32 = 1024 blocks
    pd_fused<<<grid, NT, 0, stream>>>(img, out, w1, w2);
}